// Round 4
// baseline (306.144 us; speedup 1.0000x reference)
//
#include <hip/hip_runtime.h>
#include <hip/hip_bf16.h>
#include <cstddef>

// OutputAttention: context = softmax_s(tanh(passage@W1 + hidden@W2)@Vw) . passage
// B=32, S=2048, D=512, U=512. All inputs fp32; outputs fp32.
// d_out = context[32*512] ++ attn[32*2048]. attn region doubles as score scratch.

#define NB 32
#define NS 2048
#define ND 512
#define NU 512

typedef __bf16 bf16_t;
typedef __bf16 bf16x8 __attribute__((ext_vector_type(8)));
typedef float floatx4 __attribute__((ext_vector_type(4)));

#define ROWP 136   // padded LDS row stride (128 + 8): minimal-phase bank pattern
#define SLICE (64 * ROWP)

// ---------------------------------------------------------------------------
// K0 fused: blocks [0,1024): W1 fp32->bf16 swizzle into MFMA-B frag order.
//           blocks [1024,1152): hproj[b][u] = sum_d hidden[b][d]*W2[d][u].
__global__ __launch_bounds__(256) void prep_kernel(
    const float* __restrict__ W1, bf16_t* __restrict__ W1p,
    const float* __restrict__ hidden, const float* __restrict__ W2,
    float* __restrict__ hproj) {
    if (blockIdx.x < 1024) {
        int idx = blockIdx.x * 256 + threadIdx.x;     // k*512+n
        int k = idx >> 9, n = idx & 511;
        int kc = k >> 5, q = (k >> 3) & 3, jj = k & 7;
        int ng = n >> 4, c = n & 15;
        int dst = (((kc << 5) + ng) << 9) + (q << 7) + (c << 3) + jj;
        W1p[dst] = (bf16_t)W1[idx];
    } else {
        __shared__ float h[ND];
        __shared__ float part[256];
        int bi = blockIdx.x - 1024;                   // 0..127
        int b = bi >> 2, ug = bi & 3;
        int t = threadIdx.x;
        h[t] = hidden[b * ND + t];
        h[t + 256] = hidden[b * ND + t + 256];
        __syncthreads();
        int u = (ug << 7) + (t & 127);
        int d0 = (t >> 7) << 8;                       // 0 or 256
        float acc = 0.f;
#pragma unroll 8
        for (int d = d0; d < d0 + 256; ++d) acc = fmaf(h[d], W2[d * NU + u], acc);
        part[t] = acc;
        __syncthreads();
        if (t < 128) hproj[b * NU + u] = part[t] + part[t + 128];
    }
}

// ---------------------------------------------------------------------------
// K2: scores[m] = sum_n tanh((passage@W1)[m][n] + hproj[b][n]) * Vw[n] + Vb
// m97-style pipelined K-loop: K split into 4 slices of 128; A-slice (64 rows
// x 128 k, bf16, row stride 136 for conflict-minimal LDS) double-buffered.
// Next slice's global loads issue BEFORE compute (in flight across 64 MFMAs),
// cvt + ds_write after, one barrier per slice. B-frags streamed from L2
// (pre-swizzled W1p). 8 waves x (64 rows x 64 cols), acc[4][4] = 64 AGPR.
__global__ __launch_bounds__(512, 3) void score_kernel(
    const float* __restrict__ passage, const bf16_t* __restrict__ W1p,
    const float* __restrict__ hproj, const float* __restrict__ Vw,
    const float* __restrict__ Vb, float* __restrict__ scores) {
    __shared__ bf16_t Asf[2 * SLICE];             // 34,816 B
    const int tid = threadIdx.x;
    const int wave = tid >> 6, lane = tid & 63;
    const int q = lane >> 4, c = lane & 15;
    const int m0 = blockIdx.x * 64;
    const int b = m0 >> 11;
    const int ng0 = wave << 2;
    const bf16x8* Wq = (const bf16x8*)W1p;

    // Staging assignment: thread t -> row = t>>3 (8 threads/row), 16 k each.
    const int srow = tid >> 3, skp = tid & 7;
    const float4* sbase = (const float4*)(passage + ((size_t)(m0 + srow) << 9)) + (skp << 2);
    const int swoff = srow * ROWP + (skp << 4);

#define CVT_WRITE(dst, v0, v1, v2, v3) {                                     \
    bf16x8 w0, w1;                                                           \
    w0[0] = (bf16_t)(v0).x; w0[1] = (bf16_t)(v0).y;                          \
    w0[2] = (bf16_t)(v0).z; w0[3] = (bf16_t)(v0).w;                          \
    w0[4] = (bf16_t)(v1).x; w0[5] = (bf16_t)(v1).y;                          \
    w0[6] = (bf16_t)(v1).z; w0[7] = (bf16_t)(v1).w;                          \
    w1[0] = (bf16_t)(v2).x; w1[1] = (bf16_t)(v2).y;                          \
    w1[2] = (bf16_t)(v2).z; w1[3] = (bf16_t)(v2).w;                          \
    w1[4] = (bf16_t)(v3).x; w1[5] = (bf16_t)(v3).y;                          \
    w1[6] = (bf16_t)(v3).z; w1[7] = (bf16_t)(v3).w;                          \
    *(bf16x8*)(dst) = w0; *(bf16x8*)((dst) + 8) = w1; }

    // Stage slice 0 into buffer 0.
    {
        float4 v0 = sbase[0], v1 = sbase[1], v2 = sbase[2], v3 = sbase[3];
        CVT_WRITE(Asf + swoff, v0, v1, v2, v3);
    }
    __syncthreads();

    floatx4 acc[4][4];
#pragma unroll
    for (int i = 0; i < 4; ++i)
#pragma unroll
        for (int j = 0; j < 4; ++j) { floatx4 z = {0.f, 0.f, 0.f, 0.f}; acc[i][j] = z; }

    for (int sl = 0; sl < 4; ++sl) {
        // Issue next slice's loads first — in flight during this slice's MFMAs.
        float4 p0, p1, p2, p3;
        if (sl < 3) {
            const float4* nb = sbase + ((sl + 1) << 5);
            p0 = nb[0]; p1 = nb[1]; p2 = nb[2]; p3 = nb[3];
        }
        const bf16_t* Ab = Asf + (sl & 1) * SLICE;
#pragma unroll
        for (int kcl = 0; kcl < 4; ++kcl) {
            int kc = (sl << 2) + kcl;
            bf16x8 a[4], bb[4];
#pragma unroll
            for (int i = 0; i < 4; ++i)
                a[i] = *(const bf16x8*)(Ab + (i * 16 + c) * ROWP + (((kcl << 2) + q) << 3));
#pragma unroll
            for (int j = 0; j < 4; ++j)
                bb[j] = Wq[(((kc << 5) + ng0 + j) << 6) + lane];
#pragma unroll
            for (int j = 0; j < 4; ++j)
#pragma unroll
                for (int i = 0; i < 4; ++i)
                    acc[i][j] = __builtin_amdgcn_mfma_f32_16x16x32_bf16(a[i], bb[j], acc[i][j], 0, 0, 0);
        }
        if (sl < 3) {
            bf16_t* wr = Asf + ((sl + 1) & 1) * SLICE + swoff;
            CVT_WRITE(wr, p0, p1, p2, p3);
        }
        __syncthreads();
    }
#undef CVT_WRITE

    // Epilogue: tanh(x) = 1 - 2/(1+e^{2x}); C/D layout col=c, row=i*16+q*4+r.
    float sp[4][4];
#pragma unroll
    for (int i = 0; i < 4; ++i)
#pragma unroll
        for (int r = 0; r < 4; ++r) sp[i][r] = 0.f;
#pragma unroll
    for (int j = 0; j < 4; ++j) {
        int n = (wave << 6) + (j << 4) + c;
        float hp = hproj[(b << 9) + n];
        float vw = Vw[n];
#pragma unroll
        for (int i = 0; i < 4; ++i)
#pragma unroll
            for (int r = 0; r < 4; ++r) {
                float x = acc[i][j][r] + hp;
                float e = __expf(2.0f * x);
                float t = 1.0f - 2.0f * __builtin_amdgcn_rcpf(e + 1.0f);
                sp[i][r] = fmaf(t, vw, sp[i][r]);
            }
    }
#pragma unroll
    for (int off = 1; off < 16; off <<= 1)
#pragma unroll
        for (int i = 0; i < 4; ++i)
#pragma unroll
            for (int r = 0; r < 4; ++r)
                sp[i][r] += __shfl_xor(sp[i][r], off, 64);

    float* red = (float*)Asf;                      // [8 waves][64 rows]
    if (c == 0) {
#pragma unroll
        for (int i = 0; i < 4; ++i)
#pragma unroll
            for (int r = 0; r < 4; ++r)
                red[wave * 64 + i * 16 + q * 4 + r] = sp[i][r];
    }
    __syncthreads();
    if (tid < 64) {
        float s = Vb[0];
#pragma unroll
        for (int w = 0; w < 8; ++w) s += red[w * 64 + tid];
        scores[m0 + tid] = s;
    }
}

// ---------------------------------------------------------------------------
// K3: masked softmax over S, in place on attn. 32 blocks x 1024 threads.
__global__ __launch_bounds__(1024) void softmax_kernel(
    const float* __restrict__ mask, float* __restrict__ attn) {
    __shared__ float smx[16], ssm[16];
    int b = blockIdx.x, tid = threadIdx.x;
    int wave = tid >> 6, lane = tid & 63;
    const int base = b * NS;
    float v0 = attn[base + tid] + (1.0f - mask[base + tid]) * (-1e30f);
    float v1 = attn[base + 1024 + tid] + (1.0f - mask[base + 1024 + tid]) * (-1e30f);
    float mx = fmaxf(v0, v1);
#pragma unroll
    for (int off = 1; off < 64; off <<= 1) mx = fmaxf(mx, __shfl_xor(mx, off, 64));
    if (lane == 0) smx[wave] = mx;
    __syncthreads();
    mx = smx[0];
#pragma unroll
    for (int w = 1; w < 16; ++w) mx = fmaxf(mx, smx[w]);
    v0 = __expf(v0 - mx); v1 = __expf(v1 - mx);
    float sum = v0 + v1;
#pragma unroll
    for (int off = 1; off < 64; off <<= 1) sum += __shfl_xor(sum, off, 64);
    if (lane == 0) ssm[wave] = sum;
    __syncthreads();
    sum = 0.f;
#pragma unroll
    for (int w = 0; w < 16; ++w) sum += ssm[w];
    float inv = 1.0f / sum;
    attn[base + tid] = v0 * inv;
    attn[base + 1024 + tid] = v1 * inv;
}

// ---------------------------------------------------------------------------
// K4: context[b][d] = sum_s attn[b][s] * passage[b][s][d]. 1024 blocks x 512
// threads; 4 quarter-groups of 16 s-rows accumulate in regs, LDS-combine,
// one atomic per (block, d4).
__global__ __launch_bounds__(512) void context_kernel(
    const float* __restrict__ passage, const float* __restrict__ attn,
    float* __restrict__ ctx) {
    __shared__ float4 part[512];
    int bb = blockIdx.x >> 5, sc = blockIdx.x & 31, t = threadIdx.x;
    int col = t & 127, qh = t >> 7;
    const float4* p = (const float4*)(passage + (((size_t)bb * NS + sc * 64 + qh * 16) << 9));
    const float* wp = attn + bb * NS + sc * 64 + qh * 16;
    float ax = 0.f, ay = 0.f, az = 0.f, aw = 0.f;
#pragma unroll 16
    for (int s = 0; s < 16; ++s) {
        float w = wp[s];
        float4 v = p[(size_t)s * 128 + col];
        ax = fmaf(w, v.x, ax); ay = fmaf(w, v.y, ay);
        az = fmaf(w, v.z, az); aw = fmaf(w, v.w, aw);
    }
    float4 mine; mine.x = ax; mine.y = ay; mine.z = az; mine.w = aw;
    part[t] = mine;
    __syncthreads();
    if (t < 128) {
        float4 o1 = part[t + 128], o2 = part[t + 256], o3 = part[t + 384];
        float* dst = ctx + bb * ND + t * 4;
        atomicAdd(dst + 0, ax + o1.x + o2.x + o3.x);
        atomicAdd(dst + 1, ay + o1.y + o2.y + o3.y);
        atomicAdd(dst + 2, az + o1.z + o2.z + o3.z);
        atomicAdd(dst + 3, aw + o1.w + o2.w + o3.w);
    }
}

// ---------------------------------------------------------------------------
extern "C" void kernel_launch(void* const* d_in, const int* in_sizes, int n_in,
                              void* d_out, int out_size, void* d_ws, size_t ws_size,
                              hipStream_t stream) {
    const float* passage = (const float*)d_in[0];
    const float* hidden  = (const float*)d_in[1];
    const float* mask    = (const float*)d_in[2];
    const float* W1      = (const float*)d_in[3];
    const float* W2      = (const float*)d_in[4];
    const float* Vw      = (const float*)d_in[5];
    const float* Vb      = (const float*)d_in[6];

    float* ctx  = (float*)d_out;                    // [32*512]
    float* attn = (float*)d_out + NB * ND;          // [32*2048] (score scratch)

    bf16_t* W1p  = (bf16_t*)d_ws;                               // 512KB
    float* hproj = (float*)((char*)d_ws + (size_t)NU * ND * 2); // 64KB

    hipMemsetAsync(ctx, 0, (size_t)NB * ND * sizeof(float), stream);
    prep_kernel<<<dim3(1024 + 128), dim3(256), 0, stream>>>(W1, W1p, hidden, W2, hproj);
    score_kernel<<<dim3(NB * NS / 64), dim3(512), 0, stream>>>(passage, W1p, hproj, Vw, Vb, attn);
    softmax_kernel<<<dim3(NB), dim3(1024), 0, stream>>>(mask, attn);
    context_kernel<<<dim3(NB * 32), dim3(512), 0, stream>>>(passage, attn, ctx);
}

// Round 5
// 288.241 us; speedup vs baseline: 1.0621x; 1.0621x over previous
//
#include <hip/hip_runtime.h>
#include <hip/hip_bf16.h>
#include <cstddef>

// OutputAttention: context = softmax_s(tanh(passage@W1 + hidden@W2)@Vw) . passage
// B=32, S=2048, D=512, U=512. All inputs fp32; outputs fp32.
// d_out = context[32*512] ++ attn[32*2048]. attn region doubles as score scratch.

#define NB 32
#define NS 2048
#define ND 512
#define NU 512

typedef __bf16 bf16_t;
typedef __bf16 bf16x8 __attribute__((ext_vector_type(8)));
typedef float floatx4 __attribute__((ext_vector_type(4)));

// ---------------------------------------------------------------------------
// K0 fused: blocks [0,128): W1 fp32->bf16 swizzle into MFMA-B fragment order,
//           one 1KB frag per wave: gather-reads, fully coalesced 16B writes.
//           blocks [128,256): hproj[b][u] = sum_d hidden[b][d]*W2[d][u].
// B-frag layout: frag f=(kc,ng); lane L holds B[kc*32+q*8+jj][ng*16+c], jj=0..7,
// stored at W1p[f*512 + L*8] -> k-loop reads are one 1KB dwordx4 burst/frag.
__global__ __launch_bounds__(256) void prep_kernel(
    const float* __restrict__ W1, bf16_t* __restrict__ W1p,
    const float* __restrict__ hidden, const float* __restrict__ W2,
    float* __restrict__ hproj) {
    if (blockIdx.x < 128) {
        int wave = threadIdx.x >> 6, lane = threadIdx.x & 63;
        int f = (blockIdx.x << 2) + wave;             // 0..511
        int kc = f >> 5, ng = f & 31;
        int q = lane >> 4, c = lane & 15;
        const float* src = W1 + (kc * 32 + q * 8) * 512 + ng * 16 + c;
        bf16x8 w;
#pragma unroll
        for (int jj = 0; jj < 8; ++jj) w[jj] = (bf16_t)src[jj * 512];
        ((bf16x8*)W1p)[(f << 6) + lane] = w;
    } else {
        __shared__ float h[ND];
        __shared__ float part[256];
        int bi = blockIdx.x - 128;                    // 0..127
        int b = bi >> 2, ug = bi & 3;
        int t = threadIdx.x;
        h[t] = hidden[b * ND + t];
        h[t + 256] = hidden[b * ND + t + 256];
        __syncthreads();
        int u = (ug << 7) + (t & 127);
        int d0 = (t >> 7) << 8;                       // 0 or 256
        float acc = 0.f;
#pragma unroll 8
        for (int d = d0; d < d0 + 256; ++d) acc = fmaf(h[d], W2[d * NU + u], acc);
        part[t] = acc;
        __syncthreads();
        if (t < 128) hproj[b * NU + u] = part[t] + part[t + 128];
    }
}

// ---------------------------------------------------------------------------
// K2: scores[m] = sum_n tanh((passage@W1)[m][n] + hproj[b][n]) * Vw[n] + Vb
// R3 skeleton (best measured): 64 rows/block, full-K A-tile in 64KB LDS
// (bf16, XOR swizzle), 8 waves x (64r x 64c), barrier-free k-loop, 2 blocks/CU.
// NEW: depth-2 rotating register prefetch of B-frags (the k-loop was
// concurrency-limited at 4 outstanding L2 loads/wave; depth-2 doubles it).
// Budget: 64 acc AGPR + 32 B-prefetch + 16 A + addrs ~= 124 <= 128 (4 w/SIMD).
__global__ __launch_bounds__(512, 4) void score_kernel(
    const float* __restrict__ passage, const bf16_t* __restrict__ W1p,
    const float* __restrict__ hproj, const float* __restrict__ Vw,
    const float* __restrict__ Vb, float* __restrict__ scores) {
    __shared__ bf16_t Asf[64 * 512];              // 64KB
    const int tid = threadIdx.x;
    const int wave = tid >> 6, lane = tid & 63;
    const int q = lane >> 4, c = lane & 15;
    const int m0 = blockIdx.x * 64;
    const int b = m0 >> 11;
    const int ng0 = wave << 2;
    const bf16x8* Wq = (const bf16x8*)W1p;

#define LOAD_B(dst, kc_) {                                                   \
    _Pragma("unroll")                                                        \
    for (int j = 0; j < 4; ++j)                                              \
        dst[j] = Wq[((((kc_) << 5) + ng0 + j) << 6) + lane]; }

    // B prefetch for kc=0,1 rides the staging phase / barrier drain.
    bf16x8 b0[4], b1[4];
    LOAD_B(b0, 0);
    LOAD_B(b1, 1);

    // Stage A: 64 rows x 512 k, fp32 -> bf16, chunk XOR (row&7) swizzle.
#pragma unroll
    for (int it = 0; it < 8; ++it) {
        int idx = it * 512 + tid;
        int row = idx >> 6, c8 = idx & 63;
        const float4* src = (const float4*)(passage + ((size_t)(m0 + row) << 9)) + (c8 << 1);
        float4 v0 = src[0], v1 = src[1];
        bf16x8 w;
        w[0] = (bf16_t)v0.x; w[1] = (bf16_t)v0.y; w[2] = (bf16_t)v0.z; w[3] = (bf16_t)v0.w;
        w[4] = (bf16_t)v1.x; w[5] = (bf16_t)v1.y; w[6] = (bf16_t)v1.z; w[7] = (bf16_t)v1.w;
        ((bf16x8*)(Asf + (row << 9)))[c8 ^ (row & 7)] = w;
    }
    __syncthreads();

    floatx4 acc[4][4];
#pragma unroll
    for (int i = 0; i < 4; ++i)
#pragma unroll
        for (int j = 0; j < 4; ++j) { floatx4 z = {0.f, 0.f, 0.f, 0.f}; acc[i][j] = z; }

#pragma unroll
    for (int kc = 0; kc < 16; ++kc) {
        // Issue B for kc+2 first — in flight across this iteration's MFMAs.
        bf16x8 bn[4];
        if (kc < 14) LOAD_B(bn, kc + 2);
        bf16x8 a[4];
        int chunk = (kc << 2) + q;
#pragma unroll
        for (int i = 0; i < 4; ++i)
            a[i] = ((const bf16x8*)(Asf + ((i * 16 + c) << 9)))[chunk ^ (c & 7)];
#pragma unroll
        for (int j = 0; j < 4; ++j)
#pragma unroll
            for (int i = 0; i < 4; ++i)
                acc[i][j] = __builtin_amdgcn_mfma_f32_16x16x32_bf16(a[i], b0[j], acc[i][j], 0, 0, 0);
        // Rotate (free under full unroll).
#pragma unroll
        for (int j = 0; j < 4; ++j) { b0[j] = b1[j]; b1[j] = bn[j]; }
    }
#undef LOAD_B

    // Epilogue: tanh(x) = 1 - 2/(1+e^{2x}); C/D layout col=c, row=i*16+q*4+r.
    float sp[4][4];
#pragma unroll
    for (int i = 0; i < 4; ++i)
#pragma unroll
        for (int r = 0; r < 4; ++r) sp[i][r] = 0.f;
#pragma unroll
    for (int j = 0; j < 4; ++j) {
        int n = (wave << 6) + (j << 4) + c;
        float hp = hproj[(b << 9) + n];
        float vw = Vw[n];
#pragma unroll
        for (int i = 0; i < 4; ++i)
#pragma unroll
            for (int r = 0; r < 4; ++r) {
                float x = acc[i][j][r] + hp;
                float e = __expf(2.0f * x);
                float t = 1.0f - 2.0f * __builtin_amdgcn_rcpf(e + 1.0f);
                sp[i][r] = fmaf(t, vw, sp[i][r]);
            }
    }
#pragma unroll
    for (int off = 1; off < 16; off <<= 1)
#pragma unroll
        for (int i = 0; i < 4; ++i)
#pragma unroll
            for (int r = 0; r < 4; ++r)
                sp[i][r] += __shfl_xor(sp[i][r], off, 64);

    __syncthreads();                               // all waves done with Asf
    float* red = (float*)Asf;                      // [8 waves][64 rows]
    if (c == 0) {
#pragma unroll
        for (int i = 0; i < 4; ++i)
#pragma unroll
            for (int r = 0; r < 4; ++r)
                red[wave * 64 + i * 16 + q * 4 + r] = sp[i][r];
    }
    __syncthreads();
    if (tid < 64) {
        float s = Vb[0];
#pragma unroll
        for (int w = 0; w < 8; ++w) s += red[w * 64 + tid];
        scores[m0 + tid] = s;
    }
}

// ---------------------------------------------------------------------------
// K3: masked softmax over S, in place on attn. 32 blocks x 1024 threads.
__global__ __launch_bounds__(1024) void softmax_kernel(
    const float* __restrict__ mask, float* __restrict__ attn) {
    __shared__ float smx[16], ssm[16];
    int b = blockIdx.x, tid = threadIdx.x;
    int wave = tid >> 6, lane = tid & 63;
    const int base = b * NS;
    float v0 = attn[base + tid] + (1.0f - mask[base + tid]) * (-1e30f);
    float v1 = attn[base + 1024 + tid] + (1.0f - mask[base + 1024 + tid]) * (-1e30f);
    float mx = fmaxf(v0, v1);
#pragma unroll
    for (int off = 1; off < 64; off <<= 1) mx = fmaxf(mx, __shfl_xor(mx, off, 64));
    if (lane == 0) smx[wave] = mx;
    __syncthreads();
    mx = smx[0];
#pragma unroll
    for (int w = 1; w < 16; ++w) mx = fmaxf(mx, smx[w]);
    v0 = __expf(v0 - mx); v1 = __expf(v1 - mx);
    float sum = v0 + v1;
#pragma unroll
    for (int off = 1; off < 64; off <<= 1) sum += __shfl_xor(sum, off, 64);
    if (lane == 0) ssm[wave] = sum;
    __syncthreads();
    sum = 0.f;
#pragma unroll
    for (int w = 0; w < 16; ++w) sum += ssm[w];
    float inv = 1.0f / sum;
    attn[base + tid] = v0 * inv;
    attn[base + 1024 + tid] = v1 * inv;
}

// ---------------------------------------------------------------------------
// K4: context[b][d] = sum_s attn[b][s] * passage[b][s][d]. 1024 blocks x 512
// threads; 4 quarter-groups of 16 s-rows accumulate in regs, LDS-combine,
// one atomic per (block, d4).
__global__ __launch_bounds__(512) void context_kernel(
    const float* __restrict__ passage, const float* __restrict__ attn,
    float* __restrict__ ctx) {
    __shared__ float4 part[512];
    int bb = blockIdx.x >> 5, sc = blockIdx.x & 31, t = threadIdx.x;
    int col = t & 127, qh = t >> 7;
    const float4* p = (const float4*)(passage + (((size_t)bb * NS + sc * 64 + qh * 16) << 9));
    const float* wp = attn + bb * NS + sc * 64 + qh * 16;
    float ax = 0.f, ay = 0.f, az = 0.f, aw = 0.f;
#pragma unroll 16
    for (int s = 0; s < 16; ++s) {
        float w = wp[s];
        float4 v = p[(size_t)s * 128 + col];
        ax = fmaf(w, v.x, ax); ay = fmaf(w, v.y, ay);
        az = fmaf(w, v.z, az); aw = fmaf(w, v.w, aw);
    }
    float4 mine; mine.x = ax; mine.y = ay; mine.z = az; mine.w = aw;
    part[t] = mine;
    __syncthreads();
    if (t < 128) {
        float4 o1 = part[t + 128], o2 = part[t + 256], o3 = part[t + 384];
        float* dst = ctx + bb * ND + t * 4;
        atomicAdd(dst + 0, ax + o1.x + o2.x + o3.x);
        atomicAdd(dst + 1, ay + o1.y + o2.y + o3.y);
        atomicAdd(dst + 2, az + o1.z + o2.z + o3.z);
        atomicAdd(dst + 3, aw + o1.w + o2.w + o3.w);
    }
}

// ---------------------------------------------------------------------------
extern "C" void kernel_launch(void* const* d_in, const int* in_sizes, int n_in,
                              void* d_out, int out_size, void* d_ws, size_t ws_size,
                              hipStream_t stream) {
    const float* passage = (const float*)d_in[0];
    const float* hidden  = (const float*)d_in[1];
    const float* mask    = (const float*)d_in[2];
    const float* W1      = (const float*)d_in[3];
    const float* W2      = (const float*)d_in[4];
    const float* Vw      = (const float*)d_in[5];
    const float* Vb      = (const float*)d_in[6];

    float* ctx  = (float*)d_out;                    // [32*512]
    float* attn = (float*)d_out + NB * ND;          // [32*2048] (score scratch)

    bf16_t* W1p  = (bf16_t*)d_ws;                               // 512KB
    float* hproj = (float*)((char*)d_ws + (size_t)NU * ND * 2); // 64KB

    hipMemsetAsync(ctx, 0, (size_t)NB * ND * sizeof(float), stream);
    prep_kernel<<<dim3(256), dim3(256), 0, stream>>>(W1, W1p, hidden, W2, hproj);
    score_kernel<<<dim3(NB * NS / 64), dim3(512), 0, stream>>>(passage, W1p, hproj, Vw, Vb, attn);
    softmax_kernel<<<dim3(NB), dim3(1024), 0, stream>>>(mask, attn);
    context_kernel<<<dim3(NB * 32), dim3(512), 0, stream>>>(passage, attn, ctx);
}

// Round 6
// 269.006 us; speedup vs baseline: 1.1381x; 1.0715x over previous
//
#include <hip/hip_runtime.h>
#include <hip/hip_bf16.h>
#include <cstddef>

// OutputAttention: context = softmax_s(tanh(passage@W1 + hidden@W2)@Vw) . passage
// B=32, S=2048, D=512, U=512. All inputs fp32; outputs fp32.
// d_out = context[32*512] ++ attn[32*2048]. attn region doubles as score scratch.

#define NB 32
#define NS 2048
#define ND 512
#define NU 512

typedef __bf16 bf16_t;
typedef __bf16 bf16x8 __attribute__((ext_vector_type(8)));
typedef float floatx4 __attribute__((ext_vector_type(4)));

// Async global->LDS DMA, 16B/lane (lands at lds_base + lane*16).
__device__ __forceinline__ void dma16(const void* g, void* l) {
    __builtin_amdgcn_global_load_lds(
        (const __attribute__((address_space(1))) unsigned int*)g,
        (__attribute__((address_space(3))) unsigned int*)l, 16, 0, 0);
}

// ---------------------------------------------------------------------------
// K0 fused: blocks [0,128): W1 fp32->bf16 swizzle into MFMA-B fragment order,
//           one 1KB frag per wave (gather-read, coalesced 16B writes).
//           blocks [128,256): hproj[b][u] = sum_d hidden[b][d]*W2[d][u].
// B-frag layout: frag f=(kc,ng); lane L holds B[kc*32+q*8+jj][ng*16+c], jj=0..7,
// at W1p[f*512 + L*8] -> k-loop B loads are one coalesced dwordx4 per lane.
__global__ __launch_bounds__(256) void prep_kernel(
    const float* __restrict__ W1, bf16_t* __restrict__ W1p,
    const float* __restrict__ hidden, const float* __restrict__ W2,
    float* __restrict__ hproj) {
    if (blockIdx.x < 128) {
        int wave = threadIdx.x >> 6, lane = threadIdx.x & 63;
        int f = (blockIdx.x << 2) + wave;             // 0..511
        int kc = f >> 5, ng = f & 31;
        int q = lane >> 4, c = lane & 15;
        const float* src = W1 + (kc * 32 + q * 8) * 512 + ng * 16 + c;
        bf16x8 w;
#pragma unroll
        for (int jj = 0; jj < 8; ++jj) w[jj] = (bf16_t)src[jj * 512];
        ((bf16x8*)W1p)[(f << 6) + lane] = w;
    } else {
        __shared__ float h[ND];
        __shared__ float part[256];
        int bi = blockIdx.x - 128;                    // 0..127
        int b = bi >> 2, ug = bi & 3;
        int t = threadIdx.x;
        h[t] = hidden[b * ND + t];
        h[t + 256] = hidden[b * ND + t + 256];
        __syncthreads();
        int u = (ug << 7) + (t & 127);
        int d0 = (t >> 7) << 8;                       // 0 or 256
        float acc = 0.f;
#pragma unroll 8
        for (int d = d0; d < d0 + 256; ++d) acc = fmaf(h[d], W2[d * NU + u], acc);
        part[t] = acc;
        __syncthreads();
        if (t < 128) hproj[b * NU + u] = part[t] + part[t + 128];
    }
}

// ---------------------------------------------------------------------------
// K2: scores[m] = sum_n tanh((passage@W1)[m][n] + hproj[b][n]) * Vw[n] + Vb
// kc-outer structure: K split into 16 slices of 32. A-slice (64 rows x 32 k,
// fp32) DMA'd into an LDS ring-2 via global_load_lds (no VGPR staging, no cvt
// pass); fp32->bf16 conversion at frag-read time. Per-row k-rotation
// ((kk + r) & 7) makes both DMA layout (contiguous, un-padded - required by
// global_load_lds) and frag reads ~conflict-free. Wave tile 64 rows x 128
// cols (acc[4][8] = 128 AGPR); 4 waves/block cover N=512. B-frags JIT from
// L2 in pre-swizzled order (1KB/instr, deep in flight) -> L2-BW-bound.
// One barrier per kc; its vmcnt(0) drain legalizes the ring-2 DMA handoff.
__global__ __launch_bounds__(256, 2) void score_kernel(
    const float* __restrict__ passage, const bf16_t* __restrict__ W1p,
    const float* __restrict__ hproj, const float* __restrict__ Vw,
    const float* __restrict__ Vb, float* __restrict__ scores) {
    __shared__ float ring[2 * 64 * 32];           // 2 slices x 8KB
    __shared__ float red[4 * 64];
    const int tid = threadIdx.x;
    const int wave = tid >> 6, lane = tid & 63;
    const int q = lane >> 4, c = lane & 15;
    const int m0 = blockIdx.x * 64;
    const int b = m0 >> 11;
    const int ng0 = wave << 3;                    // 8 n-tiles per wave
    const bf16x8* Wq = (const bf16x8*)W1p;

    // Staging: wave w owns chunks {2w, 2w+1} (8 rows x 32 k = 1KB each).
    // Lane l of chunk ch: r = ch*8 + (l>>3), slot = l&7, k-unit = (slot-r)&7.
    const int ch0 = wave * 2;
    const int r0 = ch0 * 8 + (lane >> 3);
    const int k0 = ((lane & 7) - r0) & 7;
    const int r1 = r0 + 8;
    const int k1 = ((lane & 7) - r1) & 7;
    const float* g0 = passage + (size_t)(m0 + r0) * ND + k0 * 4;
    const float* g1 = passage + (size_t)(m0 + r1) * ND + k1 * 4;
    char* l0a = (char*)ring + ch0 * 1024;
    char* l1a = (char*)ring + ch0 * 1024 + 1024;
    char* l0b = (char*)ring + 8192 + ch0 * 1024;
    char* l1b = (char*)ring + 8192 + ch0 * 1024 + 1024;

    // Prologue: DMA slice 0 into ring[0].
    dma16(g0, l0a);
    dma16(g1, l1a);
    __syncthreads();

    floatx4 acc[4][8];
#pragma unroll
    for (int i = 0; i < 4; ++i)
#pragma unroll
        for (int j = 0; j < 8; ++j) { floatx4 z = {0.f, 0.f, 0.f, 0.f}; acc[i][j] = z; }

    for (int kc = 0; kc < 16; ++kc) {
        // DMA next slice into the other ring half (flies across this kc's
        // compute; the end-of-kc barrier's vmcnt(0) guarantees completion).
        if (kc < 15) {
            const float* ga = g0 + (kc + 1) * 32;
            const float* gb = g1 + (kc + 1) * 32;
            if ((kc + 1) & 1) { dma16(ga, l0b); dma16(gb, l1b); }
            else              { dma16(ga, l0a); dma16(gb, l1a); }
        }
        // B-frags JIT from L2 (8 x 1KB coalesced bursts, deep in flight).
        bf16x8 bb[8];
#pragma unroll
        for (int j = 0; j < 8; ++j)
            bb[j] = Wq[(((kc << 5) + ng0 + j) << 6) + lane];
        const float* sl = ring + (kc & 1) * 2048;
#pragma unroll
        for (int i = 0; i < 4; ++i) {
            int r = i * 16 + c;
            const float* rp = sl + r * 32;
            floatx4 lo = *(const floatx4*)(rp + (((q << 1) + r) & 7) * 4);
            floatx4 hi = *(const floatx4*)(rp + (((q << 1) + 1 + r) & 7) * 4);
            bf16x8 a;
            a[0] = (bf16_t)lo[0]; a[1] = (bf16_t)lo[1];
            a[2] = (bf16_t)lo[2]; a[3] = (bf16_t)lo[3];
            a[4] = (bf16_t)hi[0]; a[5] = (bf16_t)hi[1];
            a[6] = (bf16_t)hi[2]; a[7] = (bf16_t)hi[3];
#pragma unroll
            for (int j = 0; j < 8; ++j)
                acc[i][j] = __builtin_amdgcn_mfma_f32_16x16x32_bf16(a, bb[j], acc[i][j], 0, 0, 0);
        }
        __syncthreads();
    }

    // Epilogue: tanh(x) = 1 - 2/(1+e^{2x}); C/D layout col=c, row=i*16+q*4+r.
    float sp[4][4];
#pragma unroll
    for (int i = 0; i < 4; ++i)
#pragma unroll
        for (int r = 0; r < 4; ++r) sp[i][r] = 0.f;
#pragma unroll
    for (int j = 0; j < 8; ++j) {
        int n = (wave << 7) + (j << 4) + c;
        float hp = hproj[(b << 9) + n];
        float vw = Vw[n];
#pragma unroll
        for (int i = 0; i < 4; ++i)
#pragma unroll
            for (int r = 0; r < 4; ++r) {
                float x = acc[i][j][r] + hp;
                float e = __expf(2.0f * x);
                float t = 1.0f - 2.0f * __builtin_amdgcn_rcpf(e + 1.0f);
                sp[i][r] = fmaf(t, vw, sp[i][r]);
            }
    }
#pragma unroll
    for (int off = 1; off < 16; off <<= 1)
#pragma unroll
        for (int i = 0; i < 4; ++i)
#pragma unroll
            for (int r = 0; r < 4; ++r)
                sp[i][r] += __shfl_xor(sp[i][r], off, 64);

    if (c == 0) {
#pragma unroll
        for (int i = 0; i < 4; ++i)
#pragma unroll
            for (int r = 0; r < 4; ++r)
                red[wave * 64 + i * 16 + q * 4 + r] = sp[i][r];
    }
    __syncthreads();
    if (tid < 64)
        scores[m0 + tid] = red[tid] + red[64 + tid] + red[128 + tid] + red[192 + tid] + Vb[0];
}

// ---------------------------------------------------------------------------
// K3: masked softmax over S, in place on attn. 32 blocks x 1024 threads.
__global__ __launch_bounds__(1024) void softmax_kernel(
    const float* __restrict__ mask, float* __restrict__ attn) {
    __shared__ float smx[16], ssm[16];
    int b = blockIdx.x, tid = threadIdx.x;
    int wave = tid >> 6, lane = tid & 63;
    const int base = b * NS;
    float v0 = attn[base + tid] + (1.0f - mask[base + tid]) * (-1e30f);
    float v1 = attn[base + 1024 + tid] + (1.0f - mask[base + 1024 + tid]) * (-1e30f);
    float mx = fmaxf(v0, v1);
#pragma unroll
    for (int off = 1; off < 64; off <<= 1) mx = fmaxf(mx, __shfl_xor(mx, off, 64));
    if (lane == 0) smx[wave] = mx;
    __syncthreads();
    mx = smx[0];
#pragma unroll
    for (int w = 1; w < 16; ++w) mx = fmaxf(mx, smx[w]);
    v0 = __expf(v0 - mx); v1 = __expf(v1 - mx);
    float sum = v0 + v1;
#pragma unroll
    for (int off = 1; off < 64; off <<= 1) sum += __shfl_xor(sum, off, 64);
    if (lane == 0) ssm[wave] = sum;
    __syncthreads();
    sum = 0.f;
#pragma unroll
    for (int w = 0; w < 16; ++w) sum += ssm[w];
    float inv = 1.0f / sum;
    attn[base + tid] = v0 * inv;
    attn[base + 1024 + tid] = v1 * inv;
}

// ---------------------------------------------------------------------------
// K4: context[b][d] = sum_s attn[b][s] * passage[b][s][d]. 1024 blocks x 512
// threads; 4 quarter-groups of 16 s-rows accumulate in regs, LDS-combine,
// one atomic per (block, d4).
__global__ __launch_bounds__(512) void context_kernel(
    const float* __restrict__ passage, const float* __restrict__ attn,
    float* __restrict__ ctx) {
    __shared__ float4 part[512];
    int bb = blockIdx.x >> 5, sc = blockIdx.x & 31, t = threadIdx.x;
    int col = t & 127, qh = t >> 7;
    const float4* p = (const float4*)(passage + (((size_t)bb * NS + sc * 64 + qh * 16) << 9));
    const float* wp = attn + bb * NS + sc * 64 + qh * 16;
    float ax = 0.f, ay = 0.f, az = 0.f, aw = 0.f;
#pragma unroll 16
    for (int s = 0; s < 16; ++s) {
        float w = wp[s];
        float4 v = p[(size_t)s * 128 + col];
        ax = fmaf(w, v.x, ax); ay = fmaf(w, v.y, ay);
        az = fmaf(w, v.z, az); aw = fmaf(w, v.w, aw);
    }
    float4 mine; mine.x = ax; mine.y = ay; mine.z = az; mine.w = aw;
    part[t] = mine;
    __syncthreads();
    if (t < 128) {
        float4 o1 = part[t + 128], o2 = part[t + 256], o3 = part[t + 384];
        float* dst = ctx + bb * ND + t * 4;
        atomicAdd(dst + 0, ax + o1.x + o2.x + o3.x);
        atomicAdd(dst + 1, ay + o1.y + o2.y + o3.y);
        atomicAdd(dst + 2, az + o1.z + o2.z + o3.z);
        atomicAdd(dst + 3, aw + o1.w + o2.w + o3.w);
    }
}

// ---------------------------------------------------------------------------
extern "C" void kernel_launch(void* const* d_in, const int* in_sizes, int n_in,
                              void* d_out, int out_size, void* d_ws, size_t ws_size,
                              hipStream_t stream) {
    const float* passage = (const float*)d_in[0];
    const float* hidden  = (const float*)d_in[1];
    const float* mask    = (const float*)d_in[2];
    const float* W1      = (const float*)d_in[3];
    const float* W2      = (const float*)d_in[4];
    const float* Vw      = (const float*)d_in[5];
    const float* Vb      = (const float*)d_in[6];

    float* ctx  = (float*)d_out;                    // [32*512]
    float* attn = (float*)d_out + NB * ND;          // [32*2048] (score scratch)

    bf16_t* W1p  = (bf16_t*)d_ws;                               // 512KB
    float* hproj = (float*)((char*)d_ws + (size_t)NU * ND * 2); // 64KB

    hipMemsetAsync(ctx, 0, (size_t)NB * ND * sizeof(float), stream);
    prep_kernel<<<dim3(256), dim3(256), 0, stream>>>(W1, W1p, hidden, W2, hproj);
    score_kernel<<<dim3(NB * NS / 64), dim3(256), 0, stream>>>(passage, W1p, hproj, Vw, Vb, attn);
    softmax_kernel<<<dim3(NB), dim3(1024), 0, stream>>>(mask, attn);
    context_kernel<<<dim3(NB * 32), dim3(512), 0, stream>>>(passage, attn, ctx);
}